// Round 1
// baseline (734.220 us; speedup 1.0000x reference)
//
#include <hip/hip_runtime.h>

// Greedy online bipartite matching decode.
// B=4096 rows, V=256 arrival steps, U+1=129 options (col 0 = skip, weight 0).
// One wave64 per row. Lane l owns cols l+1 and l+65; col 0 is a constant
// candidate (value 0.0 -> key 0x80000000). Mask held as 2 bits per lane.
// First skip_steps=25 steps are no-ops (sel=0, chosen=0, mask unchanged),
// so we never read those rows of x.

__device__ __forceinline__ unsigned int fkey(float f) {
    // monotone float -> uint mapping (order-preserving, invertible)
    unsigned int u = __float_as_uint(f);
    return u ^ ((unsigned int)((int)u >> 31) | 0x80000000u);
}

__device__ __forceinline__ float fkey_inv(unsigned int k) {
    return __uint_as_float((k & 0x80000000u) ? (k ^ 0x80000000u) : ~k);
}

__global__ __launch_bounds__(256, 4) void greedy_match_kernel(
    const float* __restrict__ x,
    float* __restrict__ out,   // [B] = -size, then [B*V] = pi (stored as float)
    int B)
{
    const int V = 256;
    const int SKIP = 25;
    const int ROWLEN = 129;               // U+1
    const unsigned int KZERO = 0x80000000u; // fkey(0.0f), the skip option's key

    int gtid = blockIdx.x * blockDim.x + threadIdx.x;
    int w = gtid >> 6;                    // wave id = batch row
    int lane = gtid & 63;
    if (w >= B) return;

    const float* p = x + (size_t)w * V * ROWLEN + (size_t)SKIP * ROWLEN;
    float* out_pi = out + B + (size_t)w * V;

    float acc = 0.0f;       // running matched weight (reference order, fp32)
    float pi_val = 0.0f;    // per-lane buffered sel for the current 64-step chunk
    unsigned int mask = 0;  // bit0: col lane+1 matched; bit1: col lane+65 matched

    // prefetch first active row
    float w0 = p[1 + lane];
    float w1 = p[65 + lane];

    for (int t = SKIP; t < V; ++t) {
        // prefetch next row (addresses independent of the argmax chain)
        const float* pn = p + ((t + 1 < V) ? ROWLEN : 0);
        float nw0 = pn[1 + lane];
        float nw1 = pn[65 + lane];

        // masked candidates get key 0 (< KZERO) => can never win, like NEG=-1e30
        unsigned int f0 = (mask & 1u) ? 0u : fkey(w0);
        unsigned int f1 = (mask & 2u) ? 0u : fkey(w1);
        unsigned int k = max(max(f0, f1), KZERO);
        #pragma unroll
        for (int off = 32; off > 0; off >>= 1) {
            unsigned int o = __shfl_xor(k, off, 64);
            k = max(k, o);
        }

        // first-occurrence (lowest index) tie-break, matching jnp.argmax:
        // col 0 first, then cols 1..64 (cand0), then cols 65..128 (cand1)
        int sel;
        if (k == KZERO) {
            sel = 0;
        } else {
            unsigned long long b0 = __ballot(f0 == k);
            if (b0) {
                sel = __ffsll(b0);            // lane+1 == ctz+1 == ffs
            } else {
                unsigned long long b1 = __ballot(f1 == k);
                sel = __ffsll(b1) + 64;       // lane+65
            }
        }

        acc += fkey_inv(k);                   // chosen weight (0.0 when sel==0)

        if (sel == lane + 1)       mask |= 1u;
        else if (sel == lane + 65) mask |= 2u;

        // buffer pi: lane (t&63) keeps this step's sel; flush 64 at a time
        if (lane == (t & 63)) pi_val = (float)sel;
        if ((t & 63) == 63) out_pi[(t & ~63) + lane] = pi_val;

        w0 = nw0; w1 = nw1;
        p += ROWLEN;
    }

    if (lane == 0) out[w] = -acc;
}

extern "C" void kernel_launch(void* const* d_in, const int* in_sizes, int n_in,
                              void* d_out, int out_size, void* d_ws, size_t ws_size,
                              hipStream_t stream) {
    const float* x = (const float*)d_in[0];
    const int V = 256, ROWLEN = 129;
    int B = in_sizes[0] / (V * ROWLEN);   // 4096
    float* out = (float*)d_out;

    int threads = 256;                    // 4 waves per block
    int blocks = (B * 64 + threads - 1) / threads;
    greedy_match_kernel<<<blocks, threads, 0, stream>>>(x, out, B);
}